// Round 3
// baseline (128.321 us; speedup 1.0000x reference)
//
#include <hip/hip_runtime.h>

typedef unsigned short ushort_t;
typedef __bf16 bf16_8 __attribute__((ext_vector_type(8)));
typedef float f32x4 __attribute__((ext_vector_type(4)));

#define VOCAB 4101
#define KPAD  4160   // 65 * 64
#define NROWS 3072   // 1024 * 3
#define HDIM  768
#define ODIM  256

// ---- helpers -------------------------------------------------------------

static __device__ __forceinline__ unsigned short f2bf(float f) {
  unsigned int u = __float_as_uint(f);
  unsigned int r = (u + 0x7fffu + ((u >> 16) & 1u)) >> 16;
  return (unsigned short)r;
}

static __device__ __forceinline__ void async_copy16(const void* g, void* l) {
  __builtin_amdgcn_global_load_lds(
      (const __attribute__((address_space(1))) void*)g,
      (__attribute__((address_space(3))) void*)l, 16, 0, 0);
}

// ---- kernel 1: per-row histogram -> bf16 integer counts + scale ----------

__global__ __launch_bounds__(256)
void hist_kernel(const int* __restrict__ X, ushort_t* __restrict__ A,
                 float* __restrict__ scales) {
  const int r = blockIdx.x;
  __shared__ unsigned int h[KPAD];
  for (int i = threadIdx.x; i < KPAD; i += 256) h[i] = 0u;
  __syncthreads();

  const int4* xp = reinterpret_cast<const int4*>(X + (size_t)r * 4096);
  #pragma unroll
  for (int i = 0; i < 4; ++i) {
    int4 v = xp[i * 256 + threadIdx.x];
    atomicAdd(&h[v.x], 1u);
    atomicAdd(&h[v.y], 1u);
    atomicAdd(&h[v.z], 1u);
    atomicAdd(&h[v.w], 1u);
  }
  __syncthreads();

  const unsigned int ignored = h[0] + h[1] + h[2] + h[3] + h[4];
  const float s = 10.0f / (float)(4096u - ignored);
  if (threadIdx.x == 0) scales[r] = s;

  // packed 4B stores: two bf16 counts per uint
  unsigned int* Ar = (unsigned int*)(A + (size_t)r * KPAD);
  for (int i = threadIdx.x; i < KPAD / 2; i += 256) {
    int i0 = 2 * i, i1 = 2 * i + 1;
    unsigned int c0 = (i0 >= 5 && i0 < VOCAB) ? h[i0] : 0u;
    unsigned int c1 = (i1 >= 5 && i1 < VOCAB) ? h[i1] : 0u;   // FIX: drop ignored ids 1,3
    Ar[i] = (unsigned int)f2bf((float)c0) | ((unsigned int)f2bf((float)c1) << 16);
  }
}

// ---- kernel 2: transpose + fp32->bf16 convert: src[K][N] -> dst[N][Kpad] -

__global__ __launch_bounds__(256)
void transpose_convert(const float* __restrict__ src, ushort_t* __restrict__ dst,
                       int K, int N, int Kpad) {
  __shared__ ushort_t tile[64][65];
  const int kb = blockIdx.x * 64;
  const int nb = blockIdx.y * 64;
  const int tr = threadIdx.x >> 6;
  const int tc = threadIdx.x & 63;
  #pragma unroll
  for (int i = 0; i < 16; ++i) {
    int r = i * 4 + tr;
    int k = kb + r;
    float v = (k < K) ? src[(size_t)k * N + nb + tc] : 0.0f;
    tile[r][tc] = f2bf(v);
  }
  __syncthreads();
  #pragma unroll
  for (int i = 0; i < 16; ++i) {
    int r = i * 4 + tr;
    dst[(size_t)(nb + r) * Kpad + kb + tc] = tile[tc][r];
  }
}

// ---- split-K bf16 MFMA GEMM, 2-phase prefetch, atomic combine ------------
// C[M][N] += A[M][K_chunk] * Bt[N][K_chunk]^T
// BM=128, BN=64, BK=64, 256 thr (2x2 waves); blockIdx.z = split index.
// EPI 0: atomicAdd raw fp32 into C1ws[row*HDIM+col]
// EPI 1: atomicAdd (v + bias on split 0) into out[(row%3)*262144+(row/3)*256+col]

template <int EPI>
__global__ __launch_bounds__(256)
void gemm_splitk(const ushort_t* __restrict__ A, int lda,
                 const ushort_t* __restrict__ Bt, int ldb,
                 int ktiles,
                 const float* __restrict__ bias,
                 float* __restrict__ outp) {
  __shared__ __align__(16) ushort_t Alds[2][128 * 64];
  __shared__ __align__(16) ushort_t Blds[2][64 * 64];
  const int tid  = threadIdx.x;
  const int lane = tid & 63;
  const int wv   = tid >> 6;
  const int wr   = wv >> 1;
  const int wc   = wv & 1;
  const int m0   = blockIdx.x * 128;
  const int n0   = blockIdx.y * 64;
  const int ts   = blockIdx.z * ktiles;   // first K-tile of this split

  f32x4 acc[4][2];
  #pragma unroll
  for (int m = 0; m < 4; ++m)
    #pragma unroll
    for (int n = 0; n < 2; ++n)
      acc[m][n] = (f32x4){0.f, 0.f, 0.f, 0.f};

#define STAGE(bi, kt)                                                          \
  {                                                                            \
    const int k0_ = (kt) * 64;                                                 \
    _Pragma("unroll")                                                          \
    for (int i = 0; i < 4; ++i) {                                              \
      const int e = i * 2048 + wv * 512 + lane * 8;                            \
      const int row = e >> 6, col = e & 63;                                    \
      async_copy16(A + (size_t)(m0 + row) * lda + k0_ + col,                   \
                   (char*)&Alds[bi][0] + 2 * e);                               \
    }                                                                          \
    _Pragma("unroll")                                                          \
    for (int i = 0; i < 2; ++i) {                                              \
      const int e = i * 2048 + wv * 512 + lane * 8;                            \
      const int row = e >> 6, col = e & 63;                                    \
      async_copy16(Bt + (size_t)(n0 + row) * ldb + k0_ + col,                  \
                   (char*)&Blds[bi][0] + 2 * e);                               \
    }                                                                          \
  }

  STAGE(0, ts);
  __syncthreads();

  int cur = 0;
  for (int t = 0; t < ktiles; ++t) {
    if (t + 1 < ktiles) STAGE(cur ^ 1, ts + t + 1);
    #pragma unroll
    for (int kk = 0; kk < 2; ++kk) {
      bf16_8 af[4], bfr[2];
      #pragma unroll
      for (int m = 0; m < 4; ++m)
        af[m] = *(const bf16_8*)&Alds[cur][(wr * 64 + m * 16 + (lane & 15)) * 64 +
                                           kk * 32 + (lane >> 4) * 8];
      #pragma unroll
      for (int n = 0; n < 2; ++n)
        bfr[n] = *(const bf16_8*)&Blds[cur][(wc * 32 + n * 16 + (lane & 15)) * 64 +
                                            kk * 32 + (lane >> 4) * 8];
      #pragma unroll
      for (int m = 0; m < 4; ++m)
        #pragma unroll
        for (int n = 0; n < 2; ++n)
          acc[m][n] = __builtin_amdgcn_mfma_f32_16x16x32_bf16(af[m], bfr[n],
                                                              acc[m][n], 0, 0, 0);
    }
    __syncthreads();   // drains vmcnt (prefetch) + lgkmcnt, all waves synced
    cur ^= 1;
  }
#undef STAGE

  const int rbase = (lane >> 4) * 4;
  const int cf    = lane & 15;
  #pragma unroll
  for (int m = 0; m < 4; ++m) {
    #pragma unroll
    for (int n = 0; n < 2; ++n) {
      #pragma unroll
      for (int reg = 0; reg < 4; ++reg) {
        const int gr = m0 + wr * 64 + m * 16 + rbase + reg;
        const int gc = n0 + wc * 32 + n * 16 + cf;
        float v = acc[m][n][reg];
        if constexpr (EPI == 0) {
          atomicAdd(&outp[(size_t)gr * HDIM + gc], v);
        } else {
          if (blockIdx.z == 0) v += bias[gc];
          atomicAdd(&outp[(size_t)(gr % 3) * (1024 * ODIM) +
                          (size_t)(gr / 3) * ODIM + gc], v);
        }
      }
    }
  }
}

// ---- epilogue for layer 1: scale + bias + relu -> bf16 H -----------------

__global__ __launch_bounds__(256)
void epi1_kernel(const float* __restrict__ C, const float* __restrict__ scales,
                 const float* __restrict__ bias, ushort_t* __restrict__ H) {
  const int idx4 = blockIdx.x * 256 + threadIdx.x;     // over (3072*768)/4
  const int idx  = idx4 * 4;
  const int r = idx / HDIM;
  const int c = idx % HDIM;
  const float s = scales[r];
  float4 v = *(const float4*)(C + idx);
  ushort_t o[4];
  o[0] = f2bf(fmaxf(v.x * s + bias[c + 0], 0.f));
  o[1] = f2bf(fmaxf(v.y * s + bias[c + 1], 0.f));
  o[2] = f2bf(fmaxf(v.z * s + bias[c + 2], 0.f));
  o[3] = f2bf(fmaxf(v.w * s + bias[c + 3], 0.f));
  *(uint2*)(H + idx) = *(uint2*)o;
}

// ---- launch --------------------------------------------------------------

extern "C" void kernel_launch(void* const* d_in, const int* in_sizes, int n_in,
                              void* d_out, int out_size, void* d_ws, size_t ws_size,
                              hipStream_t stream) {
  const int*   X  = (const int*)d_in[0];
  const float* W1 = (const float*)d_in[1];
  const float* b1 = (const float*)d_in[2];
  const float* W2 = (const float*)d_in[3];
  const float* b2 = (const float*)d_in[4];
  float* out = (float*)d_out;

  char* ws = (char*)d_ws;
  ushort_t* A      = (ushort_t*)(ws);                  // 25,559,040 B
  ushort_t* W1T    = (ushort_t*)(ws + 25559040);       //  6,389,760 B
  ushort_t* H      = (ushort_t*)(ws + 31948800);       //  4,718,592 B
  ushort_t* W2T    = (ushort_t*)(ws + 36667392);       //    393,216 B
  float*    scales = (float*)   (ws + 37060608);       //     12,288 B
  float*    C1ws   = (float*)   (ws + 37072896);       //  9,437,184 B -> ends 46,510,080

  hipMemsetAsync(C1ws, 0, (size_t)NROWS * HDIM * sizeof(float), stream);
  hipMemsetAsync(out, 0, (size_t)3 * 1024 * ODIM * sizeof(float), stream);

  hist_kernel<<<NROWS, 256, 0, stream>>>(X, A, scales);
  transpose_convert<<<dim3(KPAD / 64, HDIM / 64), 256, 0, stream>>>(W1, W1T, VOCAB, HDIM, KPAD);
  transpose_convert<<<dim3(HDIM / 64, ODIM / 64), 256, 0, stream>>>(W2, W2T, HDIM, ODIM, HDIM);

  // GEMM1: M=3072 N=768 K=4160 (65 tiles), split-K 5 x 13 tiles -> 1440 blocks
  gemm_splitk<0><<<dim3(NROWS / 128, HDIM / 64, 5), 256, 0, stream>>>(
      A, KPAD, W1T, KPAD, 13, nullptr, C1ws);

  epi1_kernel<<<(NROWS * HDIM / 4) / 256, 256, 0, stream>>>(C1ws, scales, b1, H);

  // GEMM2: M=3072 N=256 K=768 (12 tiles), split-K 4 x 3 tiles -> 384 blocks
  gemm_splitk<1><<<dim3(NROWS / 128, ODIM / 64, 4), 256, 0, stream>>>(
      H, HDIM, W2T, HDIM, 3, b2, out);
}

// Round 4
// 125.897 us; speedup vs baseline: 1.0193x; 1.0193x over previous
//
#include <hip/hip_runtime.h>

typedef unsigned short ushort_t;
typedef __bf16 bf16_8 __attribute__((ext_vector_type(8)));
typedef float f32x4 __attribute__((ext_vector_type(4)));

#define VOCAB 4101
#define KPAD  4160   // 65 * 64
#define NROWS 3072   // 1024 * 3
#define HDIM  768
#define ODIM  256

// ---- helpers -------------------------------------------------------------

static __device__ __forceinline__ unsigned short f2bf(float f) {
  unsigned int u = __float_as_uint(f);
  unsigned int r = (u + 0x7fffu + ((u >> 16) & 1u)) >> 16;
  return (unsigned short)r;
}

static __device__ __forceinline__ void async_copy16(const void* g, void* l) {
  __builtin_amdgcn_global_load_lds(
      (const __attribute__((address_space(1))) void*)g,
      (__attribute__((address_space(3))) void*)l, 16, 0, 0);
}

// ---- kernel 1: per-row histogram -> bf16 integer counts + scale ----------

__global__ __launch_bounds__(256)
void hist_kernel(const int* __restrict__ X, ushort_t* __restrict__ A,
                 float* __restrict__ scales) {
  const int r = blockIdx.x;
  __shared__ unsigned int h[KPAD];
  for (int i = threadIdx.x; i < KPAD; i += 256) h[i] = 0u;
  __syncthreads();

  const int4* xp = reinterpret_cast<const int4*>(X + (size_t)r * 4096);
  #pragma unroll
  for (int i = 0; i < 4; ++i) {
    int4 v = xp[i * 256 + threadIdx.x];
    atomicAdd(&h[v.x], 1u);
    atomicAdd(&h[v.y], 1u);
    atomicAdd(&h[v.z], 1u);
    atomicAdd(&h[v.w], 1u);
  }
  __syncthreads();

  const unsigned int ignored = h[0] + h[1] + h[2] + h[3] + h[4];
  const float s = 10.0f / (float)(4096u - ignored);
  if (threadIdx.x == 0) scales[r] = s;

  // packed 4B stores: two bf16 counts per uint
  unsigned int* Ar = (unsigned int*)(A + (size_t)r * KPAD);
  for (int i = threadIdx.x; i < KPAD / 2; i += 256) {
    int i0 = 2 * i, i1 = 2 * i + 1;
    unsigned int c0 = (i0 >= 5 && i0 < VOCAB) ? h[i0] : 0u;
    unsigned int c1 = (i1 >= 5 && i1 < VOCAB) ? h[i1] : 0u;
    Ar[i] = (unsigned int)f2bf((float)c0) | ((unsigned int)f2bf((float)c1) << 16);
  }
}

// ---- kernel 2: transpose + fp32->bf16 convert: src[K][N] -> dst[N][Kpad] -

__global__ __launch_bounds__(256)
void transpose_convert(const float* __restrict__ src, ushort_t* __restrict__ dst,
                       int K, int N, int Kpad) {
  __shared__ ushort_t tile[64][65];
  const int kb = blockIdx.x * 64;
  const int nb = blockIdx.y * 64;
  const int tr = threadIdx.x >> 6;
  const int tc = threadIdx.x & 63;
  #pragma unroll
  for (int i = 0; i < 16; ++i) {
    int r = i * 4 + tr;
    int k = kb + r;
    float v = (k < K) ? src[(size_t)k * N + nb + tc] : 0.0f;
    tile[r][tc] = f2bf(v);
  }
  __syncthreads();
  #pragma unroll
  for (int i = 0; i < 16; ++i) {
    int r = i * 4 + tr;
    dst[(size_t)(nb + r) * Kpad + kb + tc] = tile[tc][r];
  }
}

// ---- bf16 MFMA GEMM, 2-phase prefetch, fused epilogue, XCD-chunked -------
// C[M][N] = A[M][K] * Bt[N][K]^T ; BM=128, BN=64, BK=64, 256 thr (2x2 waves)
// Block mapping: f = blockIdx.x; xcd = f%8; p = f/8; mblk = xcd*3 + p%3;
// nblk = p/3.  Each XCD owns a 3m x (N/64)n region, m-inner order, so its
// 3 A-panels (3x1.04MB) go L2-resident and each B-panel is read once/XCD.
// EPI 0: v = relu(acc*scales[row] + bias[col]) -> bf16 H[row*HDIM+col]
// EPI 1: v = acc + bias[col] -> fp32 out[(row%3)*262144 + (row/3)*256 + col]

template <int EPI>
__global__ __launch_bounds__(256)
void gemm_fused(const ushort_t* __restrict__ A, int lda,
                const ushort_t* __restrict__ Bt, int ldb,
                int ktiles,
                const float* __restrict__ scales,
                const float* __restrict__ bias,
                void* __restrict__ outp) {
  __shared__ __align__(16) ushort_t Alds[2][128 * 64];
  __shared__ __align__(16) ushort_t Blds[2][64 * 64];
  const int tid  = threadIdx.x;
  const int lane = tid & 63;
  const int wv   = tid >> 6;
  const int wr   = wv >> 1;
  const int wc   = wv & 1;

  const int f    = blockIdx.x;
  const int xcd  = f & 7;
  const int p    = f >> 3;
  const int mblk = xcd * 3 + (p % 3);   // 24 m-blocks = 8 XCDs * 3
  const int nblk = p / 3;
  const int m0   = mblk * 128;
  const int n0   = nblk * 64;

  f32x4 acc[4][2];
  #pragma unroll
  for (int m = 0; m < 4; ++m)
    #pragma unroll
    for (int n = 0; n < 2; ++n)
      acc[m][n] = (f32x4){0.f, 0.f, 0.f, 0.f};

#define STAGE(bi, kt)                                                          \
  {                                                                            \
    const int k0_ = (kt) * 64;                                                 \
    _Pragma("unroll")                                                          \
    for (int i = 0; i < 4; ++i) {                                              \
      const int e = i * 2048 + wv * 512 + lane * 8;                            \
      const int row = e >> 6, col = e & 63;                                    \
      async_copy16(A + (size_t)(m0 + row) * lda + k0_ + col,                   \
                   (char*)&Alds[bi][0] + 2 * e);                               \
    }                                                                          \
    _Pragma("unroll")                                                          \
    for (int i = 0; i < 2; ++i) {                                              \
      const int e = i * 2048 + wv * 512 + lane * 8;                            \
      const int row = e >> 6, col = e & 63;                                    \
      async_copy16(Bt + (size_t)(n0 + row) * ldb + k0_ + col,                  \
                   (char*)&Blds[bi][0] + 2 * e);                               \
    }                                                                          \
  }

  STAGE(0, 0);
  __syncthreads();

  int cur = 0;
  for (int t = 0; t < ktiles; ++t) {
    if (t + 1 < ktiles) STAGE(cur ^ 1, t + 1);
    #pragma unroll
    for (int kk = 0; kk < 2; ++kk) {
      bf16_8 af[4], bfr[2];
      #pragma unroll
      for (int m = 0; m < 4; ++m)
        af[m] = *(const bf16_8*)&Alds[cur][(wr * 64 + m * 16 + (lane & 15)) * 64 +
                                           kk * 32 + (lane >> 4) * 8];
      #pragma unroll
      for (int n = 0; n < 2; ++n)
        bfr[n] = *(const bf16_8*)&Blds[cur][(wc * 32 + n * 16 + (lane & 15)) * 64 +
                                            kk * 32 + (lane >> 4) * 8];
      #pragma unroll
      for (int m = 0; m < 4; ++m)
        #pragma unroll
        for (int n = 0; n < 2; ++n)
          acc[m][n] = __builtin_amdgcn_mfma_f32_16x16x32_bf16(af[m], bfr[n],
                                                              acc[m][n], 0, 0, 0);
    }
    __syncthreads();   // drains vmcnt (prefetch) + lgkmcnt, all waves synced
    cur ^= 1;
  }
#undef STAGE

  // epilogue: D col = lane&15, row = 4*(lane>>4)+reg
  const int rbase = (lane >> 4) * 4;
  const int cf    = lane & 15;
  #pragma unroll
  for (int m = 0; m < 4; ++m) {
    #pragma unroll
    for (int n = 0; n < 2; ++n) {
      #pragma unroll
      for (int reg = 0; reg < 4; ++reg) {
        const int gr = m0 + wr * 64 + m * 16 + rbase + reg;
        const int gc = n0 + wc * 32 + n * 16 + cf;
        float v = acc[m][n][reg];
        if constexpr (EPI == 0) {
          v = fmaxf(v * scales[gr] + bias[gc], 0.0f);
          ((ushort_t*)outp)[(size_t)gr * HDIM + gc] = f2bf(v);
        } else {
          v += bias[gc];
          ((float*)outp)[(size_t)(gr % 3) * (1024 * ODIM) +
                         (size_t)(gr / 3) * ODIM + gc] = v;
        }
      }
    }
  }
}

// ---- launch --------------------------------------------------------------

extern "C" void kernel_launch(void* const* d_in, const int* in_sizes, int n_in,
                              void* d_out, int out_size, void* d_ws, size_t ws_size,
                              hipStream_t stream) {
  const int*   X  = (const int*)d_in[0];
  const float* W1 = (const float*)d_in[1];
  const float* b1 = (const float*)d_in[2];
  const float* W2 = (const float*)d_in[3];
  const float* b2 = (const float*)d_in[4];
  float* out = (float*)d_out;

  char* ws = (char*)d_ws;
  ushort_t* A      = (ushort_t*)(ws);                  // 25,559,040 B
  ushort_t* W1T    = (ushort_t*)(ws + 25559040);       //  6,389,760 B
  ushort_t* H      = (ushort_t*)(ws + 31948800);       //  4,718,592 B
  ushort_t* W2T    = (ushort_t*)(ws + 36667392);       //    393,216 B
  float*    scales = (float*)   (ws + 37060608);       //     12,288 B

  hist_kernel<<<NROWS, 256, 0, stream>>>(X, A, scales);
  transpose_convert<<<dim3(KPAD / 64, HDIM / 64), 256, 0, stream>>>(W1, W1T, VOCAB, HDIM, KPAD);
  transpose_convert<<<dim3(HDIM / 64, ODIM / 64), 256, 0, stream>>>(W2, W2T, HDIM, ODIM, HDIM);

  // GEMM1: M=3072 N=768 K=4160 (65 tiles); grid 288 = 8 XCD * (3m x 12n)
  gemm_fused<0><<<288, 256, 0, stream>>>(
      A, KPAD, W1T, KPAD, KPAD / 64, scales, b1, (void*)H);

  // GEMM2: M=3072 N=256 K=768 (12 tiles); grid 96 = 8 XCD * (3m x 4n)
  gemm_fused<1><<<96, 256, 0, stream>>>(
      H, HDIM, W2T, HDIM, HDIM / 64, nullptr, b2, (void*)out);
}

// Round 5
// 94.121 us; speedup vs baseline: 1.3634x; 1.3376x over previous
//
#include <hip/hip_runtime.h>

typedef unsigned short ushort_t;
typedef __bf16 bf16_8 __attribute__((ext_vector_type(8)));
typedef float f32x4 __attribute__((ext_vector_type(4)));

#define VOCAB 4101
#define KPAD  4160   // 65 * 64
#define NROWS 3072   // 1024 * 3
#define HDIM  768
#define ODIM  256

// ---- helpers -------------------------------------------------------------

static __device__ __forceinline__ unsigned short f2bf(float f) {
  unsigned int u = __float_as_uint(f);
  unsigned int r = (u + 0x7fffu + ((u >> 16) & 1u)) >> 16;
  return (unsigned short)r;
}

static __device__ __forceinline__ void async_copy16(const void* g, void* l) {
  __builtin_amdgcn_global_load_lds(
      (const __attribute__((address_space(1))) void*)g,
      (__attribute__((address_space(3))) void*)l, 16, 0, 0);
}

// ---- kernel 1: per-row histogram -> bf16 integer counts + scale ----------

__global__ __launch_bounds__(256)
void hist_kernel(const int* __restrict__ X, ushort_t* __restrict__ A,
                 float* __restrict__ scales) {
  const int r = blockIdx.x;
  __shared__ unsigned int h[KPAD];
  for (int i = threadIdx.x; i < KPAD; i += 256) h[i] = 0u;
  __syncthreads();

  const int4* xp = reinterpret_cast<const int4*>(X + (size_t)r * 4096);
  #pragma unroll
  for (int i = 0; i < 4; ++i) {
    int4 v = xp[i * 256 + threadIdx.x];
    atomicAdd(&h[v.x], 1u);
    atomicAdd(&h[v.y], 1u);
    atomicAdd(&h[v.z], 1u);
    atomicAdd(&h[v.w], 1u);
  }
  __syncthreads();

  const unsigned int ignored = h[0] + h[1] + h[2] + h[3] + h[4];
  const float s = 10.0f / (float)(4096u - ignored);
  if (threadIdx.x == 0) scales[r] = s;

  unsigned int* Ar = (unsigned int*)(A + (size_t)r * KPAD);
  for (int i = threadIdx.x; i < KPAD / 2; i += 256) {
    int i0 = 2 * i, i1 = 2 * i + 1;
    unsigned int c0 = (i0 >= 5 && i0 < VOCAB) ? h[i0] : 0u;
    unsigned int c1 = (i1 >= 5 && i1 < VOCAB) ? h[i1] : 0u;
    Ar[i] = (unsigned int)f2bf((float)c0) | ((unsigned int)f2bf((float)c1) << 16);
  }
}

// ---- kernel 2: transpose + fp32->bf16 convert: src[K][N] -> dst[N][Kpad] -

__global__ __launch_bounds__(256)
void transpose_convert(const float* __restrict__ src, ushort_t* __restrict__ dst,
                       int K, int N, int Kpad) {
  __shared__ ushort_t tile[64][65];
  const int kb = blockIdx.x * 64;
  const int nb = blockIdx.y * 64;
  const int tr = threadIdx.x >> 6;
  const int tc = threadIdx.x & 63;
  #pragma unroll
  for (int i = 0; i < 16; ++i) {
    int r = i * 4 + tr;
    int k = kb + r;
    float v = (k < K) ? src[(size_t)k * N + nb + tc] : 0.0f;
    tile[r][tc] = f2bf(v);
  }
  __syncthreads();
  #pragma unroll
  for (int i = 0; i < 16; ++i) {
    int r = i * 4 + tr;
    dst[(size_t)(nb + r) * Kpad + kb + tc] = tile[tc][r];
  }
}

// ---- bf16 MFMA GEMM, XOR-swizzled LDS, 512 thr (2m x 4n waves) -----------
// C[M][N] = A[M][K] * Bt[N][K]^T ; BM=128, BN=64, BK=64.
// LDS swizzle (T2, rule #21 both-sides): 16B chunk c at row r lives at
// chunk (c ^ (r&7)). gload_lds dest stays LINEAR (base+lane*16); the global
// SOURCE per lane is pre-permuted; ds_read applies the same XOR.
// EPI 0: v = relu(acc*scales[row] + bias[col]) -> bf16 H[row*HDIM+col]
// EPI 1: v = acc + bias[col] -> fp32 out[(row%3)*262144 + (row/3)*256 + col]

template <int EPI>
__global__ __launch_bounds__(512)
void gemm_fused(const ushort_t* __restrict__ A, int lda,
                const ushort_t* __restrict__ Bt, int ldb,
                int ktiles,
                const float* __restrict__ scales,
                const float* __restrict__ bias,
                void* __restrict__ outp) {
  __shared__ __align__(16) ushort_t Alds[2][128 * 64];   // 2 x 16 KB
  __shared__ __align__(16) ushort_t Blds[2][64 * 64];    // 2 x  8 KB
  const int tid  = threadIdx.x;
  const int lane = tid & 63;
  const int wv   = tid >> 6;      // 0..7
  const int wr   = wv >> 2;       // 0..1  -> 64 rows each
  const int wc   = wv & 3;        // 0..3  -> 16 cols each
  const int m0   = blockIdx.x * 128;
  const int n0   = blockIdx.y * 64;

  f32x4 acc[4];
  #pragma unroll
  for (int m = 0; m < 4; ++m) acc[m] = (f32x4){0.f, 0.f, 0.f, 0.f};

  // A tile: 1024 16B-chunks (8 chunks/row); B tile: 512 chunks.
#define STAGE(bi, kt)                                                          \
  {                                                                            \
    const int k0_ = (kt) * 64;                                                 \
    _Pragma("unroll")                                                          \
    for (int i = 0; i < 2; ++i) {                                              \
      const int cd  = i * 512 + tid;            /* dest chunk (linear) */      \
      const int row = cd >> 3;                                                 \
      const int cc  = (cd & 7) ^ (row & 7);     /* swizzled source chunk */    \
      async_copy16(A + (size_t)(m0 + row) * lda + k0_ + cc * 8,                \
                   (char*)&Alds[bi][0] + cd * 16);                             \
    }                                                                          \
    {                                                                          \
      const int cd  = tid;                                                     \
      const int row = cd >> 3;                                                 \
      const int cc  = (cd & 7) ^ (row & 7);                                    \
      async_copy16(Bt + (size_t)(n0 + row) * ldb + k0_ + cc * 8,               \
                   (char*)&Blds[bi][0] + cd * 16);                             \
    }                                                                          \
  }

  STAGE(0, 0);
  __syncthreads();

  int cur = 0;
  for (int t = 0; t < ktiles; ++t) {
    if (t + 1 < ktiles) STAGE(cur ^ 1, t + 1);
    #pragma unroll
    for (int kk = 0; kk < 2; ++kk) {
      bf16_8 af[4], bf;
      const int hi = lane >> 4;                  // 0..3
      #pragma unroll
      for (int m = 0; m < 4; ++m) {
        const int ra = wr * 64 + m * 16 + (lane & 15);
        const int ca = kk * 4 + hi;              // chunk col 0..7
        af[m] = *(const bf16_8*)((const char*)&Alds[cur][0] +
                                 (ra * 8 + (ca ^ (ra & 7))) * 16);
      }
      {
        const int rb = wc * 16 + (lane & 15);
        const int cb = kk * 4 + hi;
        bf = *(const bf16_8*)((const char*)&Blds[cur][0] +
                              (rb * 8 + (cb ^ (rb & 7))) * 16);
      }
      #pragma unroll
      for (int m = 0; m < 4; ++m)
        acc[m] = __builtin_amdgcn_mfma_f32_16x16x32_bf16(af[m], bf, acc[m], 0, 0, 0);
    }
    __syncthreads();
    cur ^= 1;
  }
#undef STAGE

  // epilogue: D col = lane&15, row = 4*(lane>>4)+reg
  const int rbase = (lane >> 4) * 4;
  const int cf    = lane & 15;
  #pragma unroll
  for (int m = 0; m < 4; ++m) {
    #pragma unroll
    for (int reg = 0; reg < 4; ++reg) {
      const int gr = m0 + wr * 64 + m * 16 + rbase + reg;
      const int gc = n0 + wc * 16 + cf;
      float v = acc[m][reg];
      if constexpr (EPI == 0) {
        v = fmaxf(v * scales[gr] + bias[gc], 0.0f);
        ((ushort_t*)outp)[(size_t)gr * HDIM + gc] = f2bf(v);
      } else {
        v += bias[gc];
        ((float*)outp)[(size_t)(gr % 3) * (1024 * ODIM) +
                       (size_t)(gr / 3) * ODIM + gc] = v;
      }
    }
  }
}

// ---- launch --------------------------------------------------------------

extern "C" void kernel_launch(void* const* d_in, const int* in_sizes, int n_in,
                              void* d_out, int out_size, void* d_ws, size_t ws_size,
                              hipStream_t stream) {
  const int*   X  = (const int*)d_in[0];
  const float* W1 = (const float*)d_in[1];
  const float* b1 = (const float*)d_in[2];
  const float* W2 = (const float*)d_in[3];
  const float* b2 = (const float*)d_in[4];
  float* out = (float*)d_out;

  char* ws = (char*)d_ws;
  ushort_t* A      = (ushort_t*)(ws);                  // 25,559,040 B
  ushort_t* W1T    = (ushort_t*)(ws + 25559040);       //  6,389,760 B
  ushort_t* H      = (ushort_t*)(ws + 31948800);       //  4,718,592 B
  ushort_t* W2T    = (ushort_t*)(ws + 36667392);       //    393,216 B
  float*    scales = (float*)   (ws + 37060608);       //     12,288 B

  hist_kernel<<<NROWS, 256, 0, stream>>>(X, A, scales);
  transpose_convert<<<dim3(KPAD / 64, HDIM / 64), 256, 0, stream>>>(W1, W1T, VOCAB, HDIM, KPAD);
  transpose_convert<<<dim3(HDIM / 64, ODIM / 64), 256, 0, stream>>>(W2, W2T, HDIM, ODIM, HDIM);

  // GEMM1: M=3072 N=768 K=4160 (65 tiles); grid (24 m, 12 n)
  gemm_fused<0><<<dim3(NROWS / 128, HDIM / 64), 512, 0, stream>>>(
      A, KPAD, W1T, KPAD, KPAD / 64, scales, b1, (void*)H);

  // GEMM2: M=3072 N=256 K=768 (12 tiles); grid (24 m, 4 n)
  gemm_fused<1><<<dim3(NROWS / 128, ODIM / 64), 512, 0, stream>>>(
      H, HDIM, W2T, HDIM, HDIM / 64, nullptr, b2, (void*)out);
}